// Round 2
// baseline (1157.931 us; speedup 1.0000x reference)
//
#include <hip/hip_runtime.h>
#include <hip/hip_bf16.h>
#include <stdint.h>

// Problem constants (fixed by setup_inputs)
#define NB    8
#define LQ    2048
#define LKK   2048
#define EMBD  1024

typedef __bf16 bf16_t;
typedef __bf16 bf16x8 __attribute__((ext_vector_type(8)));
typedef __bf16 bf16x4 __attribute__((ext_vector_type(4)));
typedef float  f32x4  __attribute__((ext_vector_type(4)));

// RNE float->bf16, branch-free (inputs are finite)
__device__ __forceinline__ bf16_t f2bf(float x) {
  union { float f; uint32_t u; } v; v.f = x;
  uint32_t r = v.u + 0x7fffu + ((v.u >> 16) & 1u);
  uint16_t h = (uint16_t)(r >> 16);
  return __builtin_bit_cast(bf16_t, h);
}

__device__ __forceinline__ float wred_sum(float v) {
#pragma unroll
  for (int o = 32; o; o >>= 1) v += __shfl_xor(v, o);
  return v;
}
__device__ __forceinline__ float wred_max(float v) {
#pragma unroll
  for (int o = 32; o; o >>= 1) v = fmaxf(v, __shfl_xor(v, o));
  return v;
}

// ---------------------------------------------------------------------------
// NT GEMM: C[M,N] = A[M,K] @ B[N,K]^T   (A,B bf16 row-major, f32 acc)
// m97-style: 128x128 tile, BK=32, 4 waves each 64x64, mfma_f32_16x16x32_bf16,
// global_load_lds width=16, 2 barriers per K-step.
// LDS layout K-quarter-major [kq][row][8 bf16]: linear in global_load_lds slot
// order (base + lane*16) AND conflict-free on ds_read_b128 (lanes 0..15 hit
// consecutive 16B slots -> 2 lanes/bank = free).
// EPI: 0 = bf16 store with scale (scores)
//      1 = bf16 store plain       (attn out)
//      2 = +bias, ReLU, bf16      (FFN1)
//      3 = +bias, f32 store       (FFN2)
// ---------------------------------------------------------------------------
template<int EPI>
__global__ __launch_bounds__(256, 2)
void gemm_nt(const bf16_t* __restrict__ A, const bf16_t* __restrict__ B,
             float* __restrict__ Cf, bf16_t* __restrict__ Cb,
             const float* __restrict__ bias, float scale,
             int M, int N, int K)
{
  __shared__ __align__(16) bf16_t Al[4][128][8];
  __shared__ __align__(16) bf16_t Bl[4][128][8];

  const int tid  = threadIdx.x;
  const int lane = tid & 63;
  const int wave = tid >> 6;

  const int bm = blockIdx.x * 128;
  const int bn = blockIdx.y * 128;
  const int wm = (wave >> 1) * 64;   // 2x2 wave grid
  const int wn = (wave & 1) * 64;

  f32x4 acc[4][4] = {};

  // staging: thread t fills LDS slot (t + i*256); slot -> kq = slot>>7, row = slot&127
  const int srow = tid & 127;
  const int skq  = tid >> 7;          // 0 or 1; issue i adds 2*i

  // fragment read coords
  const int fr  = lane & 15;
  const int fkq = lane >> 4;

  for (int kt = 0; kt < K; kt += 32) {
#pragma unroll
    for (int i = 0; i < 2; i++) {
      __builtin_amdgcn_global_load_lds(
        (const __attribute__((address_space(1))) void*)(A + (long)(bm + srow) * K + kt + (skq + 2*i) * 8),
        (__attribute__((address_space(3))) void*)((char*)&Al[0][0][0] + i * 4096 + wave * 1024),
        16, 0, 0);
      __builtin_amdgcn_global_load_lds(
        (const __attribute__((address_space(1))) void*)(B + (long)(bn + srow) * K + kt + (skq + 2*i) * 8),
        (__attribute__((address_space(3))) void*)((char*)&Bl[0][0][0] + i * 4096 + wave * 1024),
        16, 0, 0);
    }
    __syncthreads();   // compiler drains vmcnt before s_barrier

    bf16x8 afrag[4], bfrag[4];
#pragma unroll
    for (int m = 0; m < 4; m++) afrag[m] = *(const bf16x8*)&Al[fkq][wm + m * 16 + fr][0];
#pragma unroll
    for (int n = 0; n < 4; n++) bfrag[n] = *(const bf16x8*)&Bl[fkq][wn + n * 16 + fr][0];

#pragma unroll
    for (int m = 0; m < 4; m++)
#pragma unroll
      for (int n = 0; n < 4; n++)
        acc[m][n] = __builtin_amdgcn_mfma_f32_16x16x32_bf16(afrag[m], bfrag[n], acc[m][n], 0, 0, 0);
    __syncthreads();
  }

  // C/D layout (m89-verified): col = lane&15, row = (lane>>4)*4 + j
  const int r0 = bm + wm + ((lane >> 4) << 2);
  const int c0 = bn + wn + (lane & 15);
#pragma unroll
  for (int n = 0; n < 4; n++) {
    const int col = c0 + n * 16;
    float bv = 0.0f;
    if constexpr (EPI >= 2) bv = bias[col];
#pragma unroll
    for (int m = 0; m < 4; m++) {
#pragma unroll
      for (int j = 0; j < 4; j++) {
        const int row = r0 + m * 16 + j;
        const long idx = (long)row * N + col;
        float v = acc[m][n][j];
        if constexpr (EPI == 0)      { Cb[idx] = f2bf(v * scale); }
        else if constexpr (EPI == 1) { Cb[idx] = f2bf(v); }
        else if constexpr (EPI == 2) { v += bv; Cb[idx] = f2bf(fmaxf(v, 0.0f)); }
        else                         { v += bv; Cf[idx] = v; }
      }
    }
  }
}

// ---------------------------------------------------------------------------
// Row softmax over S [LQ][LKK] bf16 (already scaled by 1/32) -> P bf16.
// key mask pre-softmax -> NEG_INF; query mask post-softmax multiply.
// One block per row; thread t owns columns [8t, 8t+8).
// ---------------------------------------------------------------------------
__global__ __launch_bounds__(256)
void softmax_kernel(const bf16_t* __restrict__ S, bf16_t* __restrict__ P,
                    const float* __restrict__ km, const float* __restrict__ qm)
{
  __shared__ float red[8];
  const int r = blockIdx.x;
  const int t = threadIdx.x;
  const bf16_t* row = S + (long)r * LKK;

  const bf16x8 sv = *(const bf16x8*)(row + t * 8);
  const float4 k0 = ((const float4*)km)[2 * t];
  const float4 k1 = ((const float4*)km)[2 * t + 1];
  const float kmv[8] = {k0.x, k0.y, k0.z, k0.w, k1.x, k1.y, k1.z, k1.w};

  float v[8];
  float mx = -3.4e38f;
#pragma unroll
  for (int i = 0; i < 8; i++) {
    float s = (float)sv[i];
    s = (kmv[i] == 0.0f) ? -4294967295.0f : s;   // NEG_INF
    v[i] = s;
    mx = fmaxf(mx, s);
  }
  mx = wred_max(mx);
  if ((t & 63) == 0) red[t >> 6] = mx;
  __syncthreads();
  mx = fmaxf(fmaxf(red[0], red[1]), fmaxf(red[2], red[3]));

  float sum = 0.0f;
#pragma unroll
  for (int i = 0; i < 8; i++) {
    const float e = __expf(v[i] - mx);
    v[i] = e;
    sum += e;
  }
  sum = wred_sum(sum);
  if ((t & 63) == 0) red[4 + (t >> 6)] = sum;
  __syncthreads();
  sum = red[4] + red[5] + red[6] + red[7];

  const float rs = qm[r] / sum;
  bf16x8 o;
#pragma unroll
  for (int i = 0; i < 8; i++) o[i] = f2bf(v[i] * rs);
  *(bf16x8*)(P + (long)r * LKK + t * 8) = o;
}

// ---------------------------------------------------------------------------
// Fused residual + LayerNorm over rows of EMBD=1024: Y = LN(X + R)*w + b
// MODE bit0: X bf16 (else f32); bit1: R bf16; bit2: Y bf16 (else f32).
// In-place (Y==X) is safe: per-thread same-address read-then-write.
// ---------------------------------------------------------------------------
template<int MODE>
__global__ __launch_bounds__(256)
void ln_kernel(const void* __restrict__ Xv, const void* __restrict__ Rv,
               const float* __restrict__ w, const float* __restrict__ bp,
               void* __restrict__ Yv)
{
  __shared__ float red[8];
  const long r = blockIdx.x;
  const int t = threadIdx.x;

  float x0, x1, x2, x3;
  if constexpr (MODE & 1) {
    const bf16x4 xv = ((const bf16x4*)((const bf16_t*)Xv + r * EMBD))[t];
    x0 = (float)xv[0]; x1 = (float)xv[1]; x2 = (float)xv[2]; x3 = (float)xv[3];
  } else {
    const float4 xv = ((const float4*)((const float*)Xv + r * EMBD))[t];
    x0 = xv.x; x1 = xv.y; x2 = xv.z; x3 = xv.w;
  }
  float r0, r1, r2, r3;
  if constexpr (MODE & 2) {
    const bf16x4 rv = ((const bf16x4*)((const bf16_t*)Rv + r * EMBD))[t];
    r0 = (float)rv[0]; r1 = (float)rv[1]; r2 = (float)rv[2]; r3 = (float)rv[3];
  } else {
    const float4 rv = ((const float4*)((const float*)Rv + r * EMBD))[t];
    r0 = rv.x; r1 = rv.y; r2 = rv.z; r3 = rv.w;
  }
  const float s0 = x0 + r0, s1 = x1 + r1, s2 = x2 + r2, s3 = x3 + r3;

  float sum = wred_sum(s0 + s1 + s2 + s3);
  if ((t & 63) == 0) red[t >> 6] = sum;
  __syncthreads();
  const float mu = (red[0] + red[1] + red[2] + red[3]) * (1.0f / EMBD);

  const float d0 = s0 - mu, d1 = s1 - mu, d2 = s2 - mu, d3 = s3 - mu;
  float sq = wred_sum(d0 * d0 + d1 * d1 + d2 * d2 + d3 * d3);
  if ((t & 63) == 0) red[4 + (t >> 6)] = sq;
  __syncthreads();
  const float var = (red[4] + red[5] + red[6] + red[7]) * (1.0f / EMBD);
  const float rstd = rsqrtf(var + 1e-5f);

  const float4 wv = ((const float4*)w)[t];
  const float4 bv = ((const float4*)bp)[t];
  const float y0 = d0 * rstd * wv.x + bv.x;
  const float y1 = d1 * rstd * wv.y + bv.y;
  const float y2 = d2 * rstd * wv.z + bv.z;
  const float y3 = d3 * rstd * wv.w + bv.w;

  if constexpr (MODE & 4) {
    bf16x4 o; o[0] = f2bf(y0); o[1] = f2bf(y1); o[2] = f2bf(y2); o[3] = f2bf(y3);
    ((bf16x4*)((bf16_t*)Yv + r * EMBD))[t] = o;
  } else {
    ((float4*)((float*)Yv + r * EMBD))[t] = make_float4(y0, y1, y2, y3);
  }
}

// flat f32 -> bf16 (vectorized, grid-stride)
__global__ void cvt_kernel(const float* __restrict__ in, bf16_t* __restrict__ out, long n4)
{
  long i = (long)blockIdx.x * 256 + threadIdx.x;
  const long stride = (long)gridDim.x * 256;
  for (; i < n4; i += stride) {
    const float4 v = ((const float4*)in)[i];
    bf16x4 o; o[0] = f2bf(v.x); o[1] = f2bf(v.y); o[2] = f2bf(v.z); o[3] = f2bf(v.w);
    ((bf16x4*)out)[i] = o;
  }
}

// [rows][cols] f32 -> [cols][rows] bf16 (tiled transpose via LDS)
__global__ __launch_bounds__(256)
void transpose_cvt(const float* __restrict__ in, bf16_t* __restrict__ out,
                   int rows, int cols)
{
  __shared__ bf16_t tile[32][33];
  const int cb = blockIdx.x * 32;      // col coord
  const int rb = blockIdx.y * 32;      // row coord
  const int tx = threadIdx.x & 31;
  const int ty = threadIdx.x >> 5;     // 0..7
#pragma unroll
  for (int i = 0; i < 4; i++) {
    const int rr = ty + i * 8;
    tile[rr][tx] = f2bf(in[(long)(rb + rr) * cols + cb + tx]);
  }
  __syncthreads();
#pragma unroll
  for (int i = 0; i < 4; i++) {
    const int cc = ty + i * 8;
    out[(long)(cb + cc) * rows + rb + tx] = tile[tx][cc];
  }
}

// ---------------------------------------------------------------------------
extern "C" void kernel_launch(void* const* d_in, const int* in_sizes, int n_in,
                              void* d_out, int out_size, void* d_ws, size_t ws_size,
                              hipStream_t stream)
{
  const float* q    = (const float*)d_in[0];
  const float* k    = (const float*)d_in[1];
  const float* qm   = (const float*)d_in[2];
  const float* km   = (const float*)d_in[3];
  const float* lnw  = (const float*)d_in[4];
  const float* lnb  = (const float*)d_in[5];
  const float* ln2w = (const float*)d_in[6];
  const float* ln2b = (const float*)d_in[7];
  const float* W1   = (const float*)d_in[8];
  const float* b1   = (const float*)d_in[9];
  const float* W2   = (const float*)d_in[10];
  const float* b2   = (const float*)d_in[11];

  // ---- workspace (44 MiB) ----
  // attn/xb [0,32MiB) : attention out bf16, then LN1 in-place -> x bf16
  // W1b [32,34) W2b [34,36) : weights bf16
  // h   [36,44) : FFN hidden chunk bf16 (4096 rows)
  const long NEED = 44L << 20;
  if ((long)ws_size < NEED) return;
  char* ws = (char*)d_ws;
  bf16_t* attn = (bf16_t*)ws;
  bf16_t* W1b  = (bf16_t*)(ws + (32L << 20));
  bf16_t* W2b  = (bf16_t*)(ws + (34L << 20));
  bf16_t* h    = (bf16_t*)(ws + (36L << 20));

  // ---- d_out doubles as scratch during the attention phase (64 MiB f32).
  // Sb/Pb/Qbb/Kbb/Ktb live in [0,28MiB); the FFN phase later overwrites all
  // of d_out with y chunks, then LN2 normalizes in-place. Every output byte
  // is rewritten each call -> deterministic.
  char* ob = (char*)d_out;
  bf16_t* Sb  = (bf16_t*)(ob);                 // [0,8MiB)   scores bf16 (scaled)
  bf16_t* Pb  = (bf16_t*)(ob + (8L  << 20));   // [8,16)     probs bf16
  bf16_t* Qbb = (bf16_t*)(ob + (16L << 20));   // [16,20)    Q batch bf16
  bf16_t* Kbb = (bf16_t*)(ob + (20L << 20));   // [20,24)    K batch bf16
  bf16_t* Ktb = (bf16_t*)(ob + (24L << 20));   // [24,28)    K^T batch bf16

  // weights to bf16 (once)
  cvt_kernel<<<1024, 256, 0, stream>>>(W1, W1b, (long)EMBD * EMBD / 4);
  cvt_kernel<<<1024, 256, 0, stream>>>(W2, W2b, (long)EMBD * EMBD / 4);

  // ---- attention, batch by batch ----
  const float scale = 0.03125f;   // 1/(sqrt(1024)+1e-8)
  for (int b = 0; b < NB; b++) {
    const float* qb = q + (long)b * LQ * EMBD;
    const float* kb = k + (long)b * LKK * EMBD;
    cvt_kernel<<<2048, 256, 0, stream>>>(qb, Qbb, (long)LQ * EMBD / 4);
    cvt_kernel<<<2048, 256, 0, stream>>>(kb, Kbb, (long)LKK * EMBD / 4);
    transpose_cvt<<<dim3(EMBD / 32, LKK / 32), 256, 0, stream>>>(kb, Ktb, LKK, EMBD);

    // S = (Q K^T) * 1/32  -> bf16
    gemm_nt<0><<<dim3(LQ / 128, LKK / 128), 256, 0, stream>>>(
        Qbb, Kbb, nullptr, Sb, nullptr, scale, LQ, LKK, EMBD);
    // P = qmask * softmax(mask(S))
    softmax_kernel<<<LQ, 256, 0, stream>>>(Sb, Pb, km + (long)b * LKK, qm + (long)b * LQ);
    // attn_b = P @ K
    gemm_nt<1><<<dim3(LQ / 128, EMBD / 128), 256, 0, stream>>>(
        Pb, Ktb, nullptr, attn + (long)b * LQ * EMBD, nullptr, 0.0f, LQ, EMBD, LKK);
  }

  // x = LN(attn + q)  (in-place over attn, bf16)
  ln_kernel<5><<<NB * LQ, 256, 0, stream>>>(attn, q, lnw, lnb, attn);

  // ---- FFN + LN2, in 4 row-chunks of 4096 ----
  for (int c = 0; c < 4; c++) {
    bf16_t* xc = attn + (long)c * 4096 * EMBD;
    float*  yc = (float*)d_out + (long)c * 4096 * EMBD;
    // h = relu(x W1^T + b1)
    gemm_nt<2><<<dim3(4096 / 128, EMBD / 128), 256, 0, stream>>>(
        xc, W1b, nullptr, h, b1, 0.0f, 4096, EMBD, EMBD);
    // y = h W2^T + b2  (into d_out rows)
    gemm_nt<3><<<dim3(4096 / 128, EMBD / 128), 256, 0, stream>>>(
        h, W2b, yc, nullptr, b2, 0.0f, 4096, EMBD, EMBD);
    // out = LN(y + x)  (in-place over y rows)
    ln_kernel<2><<<4096, 256, 0, stream>>>(yc, xc, ln2w, ln2b, yc);
  }
}

// Round 3
// 599.506 us; speedup vs baseline: 1.9315x; 1.9315x over previous
//
#include <hip/hip_runtime.h>
#include <hip/hip_bf16.h>
#include <stdint.h>

// Problem constants (fixed by setup_inputs)
#define NB    8
#define LQ    2048
#define LKK   2048
#define EMBD  1024

typedef __bf16 bf16_t;
typedef __bf16 bf16x8 __attribute__((ext_vector_type(8)));
typedef __bf16 bf16x4 __attribute__((ext_vector_type(4)));
typedef float  f32x4  __attribute__((ext_vector_type(4)));

// RNE float->bf16, branch-free (inputs are finite)
__device__ __forceinline__ bf16_t f2bf(float x) {
  union { float f; uint32_t u; } v; v.f = x;
  uint32_t r = v.u + 0x7fffu + ((v.u >> 16) & 1u);
  uint16_t h = (uint16_t)(r >> 16);
  return __builtin_bit_cast(bf16_t, h);
}

__device__ __forceinline__ float wred_sum(float v) {
#pragma unroll
  for (int o = 32; o; o >>= 1) v += __shfl_xor(v, o);
  return v;
}
__device__ __forceinline__ float wred_max(float v) {
#pragma unroll
  for (int o = 32; o; o >>= 1) v = fmaxf(v, __shfl_xor(v, o));
  return v;
}

// ---------------------------------------------------------------------------
// Batched NT GEMM: C[z][M,N] = A[z][M,K] @ B[z][N,K]^T  (bf16 in, f32 acc)
// m97-style: 128x128 tile, BK=32, 4 waves each 64x64, mfma_f32_16x16x32_bf16,
// global_load_lds width=16, 2 barriers per K-step.
// LDS layout K-quarter-major [kq][row][8 bf16]: linear in global_load_lds slot
// order (base + lane*16) AND conflict-free on ds_read_b128.
// EPI: 0 = bf16 store with scale (scores)
//      1 = bf16 store plain       (attn out)
//      2 = +bias, ReLU, bf16      (FFN1)
//      3 = +bias, f32 store       (FFN2)
// ---------------------------------------------------------------------------
template<int EPI>
__global__ __launch_bounds__(256, 2)
void gemm_nt(const bf16_t* __restrict__ A, const bf16_t* __restrict__ B,
             float* __restrict__ Cf, bf16_t* __restrict__ Cb,
             const float* __restrict__ bias, float scale,
             int M, int N, int K, long sA, long sB, long sC)
{
  __shared__ __align__(16) bf16_t Al[4][128][8];
  __shared__ __align__(16) bf16_t Bl[4][128][8];

  const int tid  = threadIdx.x;
  const int lane = tid & 63;
  const int wave = tid >> 6;
  const int bz   = blockIdx.z;

  const bf16_t* Ab = A + (long)bz * sA;
  const bf16_t* Bb = B + (long)bz * sB;

  const int bm = blockIdx.x * 128;
  const int bn = blockIdx.y * 128;
  const int wm = (wave >> 1) * 64;   // 2x2 wave grid
  const int wn = (wave & 1) * 64;

  f32x4 acc[4][4] = {};

  // staging: thread t fills LDS slot (t + i*256); slot -> kq = slot>>7, row = slot&127
  const int srow = tid & 127;
  const int skq  = tid >> 7;          // 0 or 1; issue i adds 2*i

  // fragment read coords
  const int fr  = lane & 15;
  const int fkq = lane >> 4;

  for (int kt = 0; kt < K; kt += 32) {
#pragma unroll
    for (int i = 0; i < 2; i++) {
      __builtin_amdgcn_global_load_lds(
        (const __attribute__((address_space(1))) void*)(Ab + (long)(bm + srow) * K + kt + (skq + 2*i) * 8),
        (__attribute__((address_space(3))) void*)((char*)&Al[0][0][0] + i * 4096 + wave * 1024),
        16, 0, 0);
      __builtin_amdgcn_global_load_lds(
        (const __attribute__((address_space(1))) void*)(Bb + (long)(bn + srow) * K + kt + (skq + 2*i) * 8),
        (__attribute__((address_space(3))) void*)((char*)&Bl[0][0][0] + i * 4096 + wave * 1024),
        16, 0, 0);
    }
    __syncthreads();   // compiler drains vmcnt before s_barrier

    bf16x8 afrag[4], bfrag[4];
#pragma unroll
    for (int m = 0; m < 4; m++) afrag[m] = *(const bf16x8*)&Al[fkq][wm + m * 16 + fr][0];
#pragma unroll
    for (int n = 0; n < 4; n++) bfrag[n] = *(const bf16x8*)&Bl[fkq][wn + n * 16 + fr][0];

#pragma unroll
    for (int m = 0; m < 4; m++)
#pragma unroll
      for (int n = 0; n < 4; n++)
        acc[m][n] = __builtin_amdgcn_mfma_f32_16x16x32_bf16(afrag[m], bfrag[n], acc[m][n], 0, 0, 0);
    __syncthreads();
  }

  // C/D layout (m89-verified): col = lane&15, row = (lane>>4)*4 + j
  const int r0 = bm + wm + ((lane >> 4) << 2);
  const int c0 = bn + wn + (lane & 15);
  const long cb = (long)bz * sC;
#pragma unroll
  for (int n = 0; n < 4; n++) {
    const int col = c0 + n * 16;
    float bv = 0.0f;
    if constexpr (EPI >= 2) bv = bias[col];
#pragma unroll
    for (int m = 0; m < 4; m++) {
#pragma unroll
      for (int j = 0; j < 4; j++) {
        const int row = r0 + m * 16 + j;
        const long idx = cb + (long)row * N + col;
        float v = acc[m][n][j];
        if constexpr (EPI == 0)      { Cb[idx] = f2bf(v * scale); }
        else if constexpr (EPI == 1) { Cb[idx] = f2bf(v); }
        else if constexpr (EPI == 2) { v += bv; Cb[idx] = f2bf(fmaxf(v, 0.0f)); }
        else                         { v += bv; Cf[idx] = v; }
      }
    }
  }
}

// ---------------------------------------------------------------------------
// Row softmax over S [(nb)*LQ][LKK] bf16 (already scaled) -> P bf16, in-place
// capable (P may == S). km/qm pointers pre-offset to the batch range.
// ---------------------------------------------------------------------------
__global__ __launch_bounds__(256)
void softmax_kernel(const bf16_t* __restrict__ S, bf16_t* __restrict__ P,
                    const float* __restrict__ km, const float* __restrict__ qm)
{
  __shared__ float red[8];
  const int r = blockIdx.x;
  const int b = r >> 11;              // local batch index (r / LQ)
  const int t = threadIdx.x;
  const bf16_t* row = S + (long)r * LKK;

  const bf16x8 sv = *(const bf16x8*)(row + t * 8);
  const float4 k0 = ((const float4*)(km + (long)b * LKK))[2 * t];
  const float4 k1 = ((const float4*)(km + (long)b * LKK))[2 * t + 1];
  const float kmv[8] = {k0.x, k0.y, k0.z, k0.w, k1.x, k1.y, k1.z, k1.w};

  float v[8];
  float mx = -3.4e38f;
#pragma unroll
  for (int i = 0; i < 8; i++) {
    float s = (float)sv[i];
    s = (kmv[i] == 0.0f) ? -4294967295.0f : s;   // NEG_INF
    v[i] = s;
    mx = fmaxf(mx, s);
  }
  mx = wred_max(mx);
  if ((t & 63) == 0) red[t >> 6] = mx;
  __syncthreads();
  mx = fmaxf(fmaxf(red[0], red[1]), fmaxf(red[2], red[3]));

  float sum = 0.0f;
#pragma unroll
  for (int i = 0; i < 8; i++) {
    const float e = __expf(v[i] - mx);
    v[i] = e;
    sum += e;
  }
  sum = wred_sum(sum);
  if ((t & 63) == 0) red[4 + (t >> 6)] = sum;
  __syncthreads();
  sum = red[4] + red[5] + red[6] + red[7];

  const float rs = qm[r] / sum;
  bf16x8 o;
#pragma unroll
  for (int i = 0; i < 8; i++) o[i] = f2bf(v[i] * rs);
  *(bf16x8*)(P + (long)r * LKK + t * 8) = o;
}

// ---------------------------------------------------------------------------
// Fused residual + LayerNorm: Y = LN(X + R)*w + b  (rows of EMBD)
// MODE bit0: X bf16 (else f32); bit1: R bf16; bit2: Y bf16 (else f32).
// In-place (Y==X) safe: per-thread same-address read-then-write.
// ---------------------------------------------------------------------------
template<int MODE>
__global__ __launch_bounds__(256)
void ln_kernel(const void* __restrict__ Xv, const void* __restrict__ Rv,
               const float* __restrict__ w, const float* __restrict__ bp,
               void* __restrict__ Yv)
{
  __shared__ float red[8];
  const long r = blockIdx.x;
  const int t = threadIdx.x;

  float x0, x1, x2, x3;
  if constexpr (MODE & 1) {
    const bf16x4 xv = ((const bf16x4*)((const bf16_t*)Xv + r * EMBD))[t];
    x0 = (float)xv[0]; x1 = (float)xv[1]; x2 = (float)xv[2]; x3 = (float)xv[3];
  } else {
    const float4 xv = ((const float4*)((const float*)Xv + r * EMBD))[t];
    x0 = xv.x; x1 = xv.y; x2 = xv.z; x3 = xv.w;
  }
  float r0, r1, r2, r3;
  if constexpr (MODE & 2) {
    const bf16x4 rv = ((const bf16x4*)((const bf16_t*)Rv + r * EMBD))[t];
    r0 = (float)rv[0]; r1 = (float)rv[1]; r2 = (float)rv[2]; r3 = (float)rv[3];
  } else {
    const float4 rv = ((const float4*)((const float*)Rv + r * EMBD))[t];
    r0 = rv.x; r1 = rv.y; r2 = rv.z; r3 = rv.w;
  }
  const float s0 = x0 + r0, s1 = x1 + r1, s2 = x2 + r2, s3 = x3 + r3;

  float sum = wred_sum(s0 + s1 + s2 + s3);
  if ((t & 63) == 0) red[t >> 6] = sum;
  __syncthreads();
  const float mu = (red[0] + red[1] + red[2] + red[3]) * (1.0f / EMBD);

  const float d0 = s0 - mu, d1 = s1 - mu, d2 = s2 - mu, d3 = s3 - mu;
  float sq = wred_sum(d0 * d0 + d1 * d1 + d2 * d2 + d3 * d3);
  if ((t & 63) == 0) red[4 + (t >> 6)] = sq;
  __syncthreads();
  const float var = (red[4] + red[5] + red[6] + red[7]) * (1.0f / EMBD);
  const float rstd = rsqrtf(var + 1e-5f);

  const float4 wv = ((const float4*)w)[t];
  const float4 bv = ((const float4*)bp)[t];
  const float y0 = d0 * rstd * wv.x + bv.x;
  const float y1 = d1 * rstd * wv.y + bv.y;
  const float y2 = d2 * rstd * wv.z + bv.z;
  const float y3 = d3 * rstd * wv.w + bv.w;

  if constexpr (MODE & 4) {
    bf16x4 o; o[0] = f2bf(y0); o[1] = f2bf(y1); o[2] = f2bf(y2); o[3] = f2bf(y3);
    ((bf16x4*)((bf16_t*)Yv + r * EMBD))[t] = o;
  } else {
    ((float4*)((float*)Yv + r * EMBD))[t] = make_float4(y0, y1, y2, y3);
  }
}

// flat f32 -> bf16 (vectorized, grid-stride)
__global__ void cvt_kernel(const float* __restrict__ in, bf16_t* __restrict__ out, long n4)
{
  long i = (long)blockIdx.x * 256 + threadIdx.x;
  const long stride = (long)gridDim.x * 256;
  for (; i < n4; i += stride) {
    const float4 v = ((const float4*)in)[i];
    bf16x4 o; o[0] = f2bf(v.x); o[1] = f2bf(v.y); o[2] = f2bf(v.z); o[3] = f2bf(v.w);
    ((bf16x4*)out)[i] = o;
  }
}

// batched [z][rows][cols] f32 -> [z][cols][rows] bf16 (tiled transpose via LDS)
__global__ __launch_bounds__(256)
void transpose_cvt(const float* __restrict__ in, bf16_t* __restrict__ out,
                   int rows, int cols)
{
  __shared__ bf16_t tile[32][33];
  const long zb = (long)blockIdx.z * rows * cols;
  const int cb = blockIdx.x * 32;      // col coord
  const int rb = blockIdx.y * 32;      // row coord
  const int tx = threadIdx.x & 31;
  const int ty = threadIdx.x >> 5;     // 0..7
#pragma unroll
  for (int i = 0; i < 4; i++) {
    const int rr = ty + i * 8;
    tile[rr][tx] = f2bf(in[zb + (long)(rb + rr) * cols + cb + tx]);
  }
  __syncthreads();
#pragma unroll
  for (int i = 0; i < 4; i++) {
    const int cc = ty + i * 8;
    out[zb + (long)(cb + cc) * rows + rb + tx] = tile[tx][cc];
  }
}

// ---------------------------------------------------------------------------
extern "C" void kernel_launch(void* const* d_in, const int* in_sizes, int n_in,
                              void* d_out, int out_size, void* d_ws, size_t ws_size,
                              hipStream_t stream)
{
  const float* q    = (const float*)d_in[0];
  const float* k    = (const float*)d_in[1];
  const float* qm   = (const float*)d_in[2];
  const float* km   = (const float*)d_in[3];
  const float* lnw  = (const float*)d_in[4];
  const float* lnb  = (const float*)d_in[5];
  const float* ln2w = (const float*)d_in[6];
  const float* ln2b = (const float*)d_in[7];
  const float* W1   = (const float*)d_in[8];
  const float* b1   = (const float*)d_in[9];
  const float* W2   = (const float*)d_in[10];
  const float* b2   = (const float*)d_in[11];

  char* ws = (char*)d_ws;
  char* ob = (char*)d_out;
  const float scale = 0.03125f;             // 1/(sqrt(1024)+1e-8)
  const long MB = 1L << 20;
  const long QE = (long)LQ * EMBD;          // 2M elems per batch (Q-shaped)
  const long SS = (long)LQ * LKK;           // 4M elems per batch (S-shaped)

  if (ws_size >= 100 * MB) {
    // ================= Tier A: fully batched (z=8) =================
    // ws:  [0,32) Qb -> attn   [32,64) Kb -> h   [64,96) Kt   [96,100) W1b,W2b
    // out: [0,64) S/P bf16 (in-place softmax) -> y f32
    bf16_t* Qb   = (bf16_t*)ws;
    bf16_t* attn = (bf16_t*)ws;                  // overlays Qb (dead after QK)
    bf16_t* Kb   = (bf16_t*)(ws + 32 * MB);
    bf16_t* h    = (bf16_t*)(ws + 32 * MB);      // overlays Kb (dead after QK)
    bf16_t* Kt   = (bf16_t*)(ws + 64 * MB);
    bf16_t* W1b  = (bf16_t*)(ws + 96 * MB);
    bf16_t* W2b  = (bf16_t*)(ws + 98 * MB);
    bf16_t* Sb   = (bf16_t*)ob;                  // 64 MiB, whole d_out
    float*  y    = (float*)ob;

    cvt_kernel<<<1024, 256, 0, stream>>>(W1, W1b, (long)EMBD * EMBD / 4);
    cvt_kernel<<<1024, 256, 0, stream>>>(W2, W2b, (long)EMBD * EMBD / 4);
    cvt_kernel<<<4096, 256, 0, stream>>>(q, Qb, (long)NB * QE / 4);
    cvt_kernel<<<4096, 256, 0, stream>>>(k, Kb, (long)NB * QE / 4);
    transpose_cvt<<<dim3(EMBD / 32, LKK / 32, NB), 256, 0, stream>>>(k, Kt, LKK, EMBD);

    // S = (Q K^T)/32
    gemm_nt<0><<<dim3(LQ / 128, LKK / 128, NB), 256, 0, stream>>>(
        Qb, Kb, nullptr, Sb, nullptr, scale, LQ, LKK, EMBD, QE, QE, SS);
    // P = qmask * softmax(mask(S))   (in-place)
    softmax_kernel<<<NB * LQ, 256, 0, stream>>>(Sb, Sb, km, qm);
    // attn = P @ K
    gemm_nt<1><<<dim3(LQ / 128, EMBD / 128, NB), 256, 0, stream>>>(
        Sb, Kt, nullptr, attn, nullptr, 0.0f, LQ, EMBD, LKK, SS, (long)EMBD * LKK, QE);
    // x = LN(attn + q) in-place
    ln_kernel<5><<<NB * LQ, 256, 0, stream>>>(attn, q, lnw, lnb, attn);
    // FFN single-shot over 16384 rows
    gemm_nt<2><<<dim3(NB * LQ / 128, EMBD / 128, 1), 256, 0, stream>>>(
        attn, W1b, nullptr, h, b1, 0.0f, NB * LQ, EMBD, EMBD, 0, 0, 0);
    gemm_nt<3><<<dim3(NB * LQ / 128, EMBD / 128, 1), 256, 0, stream>>>(
        h, W2b, y, nullptr, b2, 0.0f, NB * LQ, EMBD, EMBD, 0, 0, 0);
    // out = LN(y + x) in-place
    ln_kernel<2><<<NB * LQ, 256, 0, stream>>>(y, attn, ln2w, ln2b, y);

  } else if (ws_size >= 52 * MB) {
    // ================= Tier B: two half-batches (z=4) =================
    // ws:  [0,32) attn  [32,36) W1b,W2b  [36,52) Kth -> h(chunk)
    // out: [0,32) S/P half   [32,48) Qbh   [48,64) Kbh   -> later y f32
    bf16_t* attn = (bf16_t*)ws;
    bf16_t* W1b  = (bf16_t*)(ws + 32 * MB);
    bf16_t* W2b  = (bf16_t*)(ws + 34 * MB);
    bf16_t* Kth  = (bf16_t*)(ws + 36 * MB);
    bf16_t* h    = (bf16_t*)(ws + 36 * MB);      // overlays Kth (dead after PV)
    bf16_t* Sb   = (bf16_t*)ob;
    bf16_t* Qbh  = (bf16_t*)(ob + 32 * MB);
    bf16_t* Kbh  = (bf16_t*)(ob + 48 * MB);
    float*  y    = (float*)ob;

    cvt_kernel<<<1024, 256, 0, stream>>>(W1, W1b, (long)EMBD * EMBD / 4);
    cvt_kernel<<<1024, 256, 0, stream>>>(W2, W2b, (long)EMBD * EMBD / 4);

    for (int it = 0; it < 2; it++) {
      const int bo = it * 4;
      const float* qh = q + bo * QE;
      const float* kh = k + bo * QE;
      cvt_kernel<<<2048, 256, 0, stream>>>(qh, Qbh, 4 * QE / 4);
      cvt_kernel<<<2048, 256, 0, stream>>>(kh, Kbh, 4 * QE / 4);
      transpose_cvt<<<dim3(EMBD / 32, LKK / 32, 4), 256, 0, stream>>>(kh, Kth, LKK, EMBD);

      gemm_nt<0><<<dim3(LQ / 128, LKK / 128, 4), 256, 0, stream>>>(
          Qbh, Kbh, nullptr, Sb, nullptr, scale, LQ, LKK, EMBD, QE, QE, SS);
      softmax_kernel<<<4 * LQ, 256, 0, stream>>>(Sb, Sb, km + bo * LKK, qm + bo * LQ);
      gemm_nt<1><<<dim3(LQ / 128, EMBD / 128, 4), 256, 0, stream>>>(
          Sb, Kth, nullptr, attn + bo * QE, nullptr, 0.0f, LQ, EMBD, LKK,
          SS, (long)EMBD * LKK, QE);
    }
    ln_kernel<5><<<NB * LQ, 256, 0, stream>>>(attn, q, lnw, lnb, attn);
    // FFN in 2 chunks of 8192 rows (h chunk = 16 MiB over Kth)
    for (int c = 0; c < 2; c++) {
      bf16_t* xc = attn + (long)c * 8192 * EMBD;
      float*  yc = y + (long)c * 8192 * EMBD;
      gemm_nt<2><<<dim3(8192 / 128, EMBD / 128, 1), 256, 0, stream>>>(
          xc, W1b, nullptr, h, b1, 0.0f, 8192, EMBD, EMBD, 0, 0, 0);
      gemm_nt<3><<<dim3(8192 / 128, EMBD / 128, 1), 256, 0, stream>>>(
          h, W2b, yc, nullptr, b2, 0.0f, 8192, EMBD, EMBD, 0, 0, 0);
    }
    ln_kernel<2><<<NB * LQ, 256, 0, stream>>>(y, attn, ln2w, ln2b, y);

  } else {
    // ================= Tier C: known-good 44 MiB per-batch path =================
    if (ws_size < 44 * MB) return;
    bf16_t* attn = (bf16_t*)ws;
    bf16_t* W1b  = (bf16_t*)(ws + 32 * MB);
    bf16_t* W2b  = (bf16_t*)(ws + 34 * MB);
    bf16_t* h    = (bf16_t*)(ws + 36 * MB);
    bf16_t* Sb   = (bf16_t*)(ob);
    bf16_t* Pb   = (bf16_t*)(ob + 8 * MB);
    bf16_t* Qbb  = (bf16_t*)(ob + 16 * MB);
    bf16_t* Kbb  = (bf16_t*)(ob + 20 * MB);
    bf16_t* Ktb  = (bf16_t*)(ob + 24 * MB);

    cvt_kernel<<<1024, 256, 0, stream>>>(W1, W1b, (long)EMBD * EMBD / 4);
    cvt_kernel<<<1024, 256, 0, stream>>>(W2, W2b, (long)EMBD * EMBD / 4);

    for (int b = 0; b < NB; b++) {
      const float* qb = q + b * QE;
      const float* kb = k + b * QE;
      cvt_kernel<<<2048, 256, 0, stream>>>(qb, Qbb, QE / 4);
      cvt_kernel<<<2048, 256, 0, stream>>>(kb, Kbb, QE / 4);
      transpose_cvt<<<dim3(EMBD / 32, LKK / 32, 1), 256, 0, stream>>>(kb, Ktb, LKK, EMBD);

      gemm_nt<0><<<dim3(LQ / 128, LKK / 128, 1), 256, 0, stream>>>(
          Qbb, Kbb, nullptr, Sb, nullptr, scale, LQ, LKK, EMBD, 0, 0, 0);
      softmax_kernel<<<LQ, 256, 0, stream>>>(Sb, Pb, km + (long)b * LKK, qm + (long)b * LQ);
      gemm_nt<1><<<dim3(LQ / 128, EMBD / 128, 1), 256, 0, stream>>>(
          Pb, Ktb, nullptr, attn + b * QE, nullptr, 0.0f, LQ, EMBD, LKK, 0, 0, 0);
    }
    ln_kernel<5><<<NB * LQ, 256, 0, stream>>>(attn, q, lnw, lnb, attn);
    for (int c = 0; c < 4; c++) {
      bf16_t* xc = attn + (long)c * 4096 * EMBD;
      float*  yc = (float*)d_out + (long)c * 4096 * EMBD;
      gemm_nt<2><<<dim3(4096 / 128, EMBD / 128, 1), 256, 0, stream>>>(
          xc, W1b, nullptr, h, b1, 0.0f, 4096, EMBD, EMBD, 0, 0, 0);
      gemm_nt<3><<<dim3(4096 / 128, EMBD / 128, 1), 256, 0, stream>>>(
          h, W2b, yc, nullptr, b2, 0.0f, 4096, EMBD, EMBD, 0, 0, 0);
      ln_kernel<2><<<4096, 256, 0, stream>>>(yc, xc, ln2w, ln2b, yc);
    }
  }
}

// Round 4
// 518.601 us; speedup vs baseline: 2.2328x; 1.1560x over previous
//
#include <hip/hip_runtime.h>
#include <hip/hip_bf16.h>
#include <stdint.h>

// Problem constants (fixed by setup_inputs)
#define NB    8
#define LQ    2048
#define LKK   2048
#define EMBD  1024

typedef __bf16 bf16_t;
typedef __bf16 bf16x8 __attribute__((ext_vector_type(8)));
typedef __bf16 bf16x4 __attribute__((ext_vector_type(4)));
typedef float  f32x4  __attribute__((ext_vector_type(4)));

// RNE float->bf16, branch-free (inputs are finite)
__device__ __forceinline__ bf16_t f2bf(float x) {
  union { float f; uint32_t u; } v; v.f = x;
  uint32_t r = v.u + 0x7fffu + ((v.u >> 16) & 1u);
  uint16_t h = (uint16_t)(r >> 16);
  return __builtin_bit_cast(bf16_t, h);
}

__device__ __forceinline__ float wred_sum(float v) {
#pragma unroll
  for (int o = 32; o; o >>= 1) v += __shfl_xor(v, o);
  return v;
}
__device__ __forceinline__ float wred_max(float v) {
#pragma unroll
  for (int o = 32; o; o >>= 1) v = fmaxf(v, __shfl_xor(v, o));
  return v;
}

// ---------------------------------------------------------------------------
// Batched NT GEMM: C[z][M,N] = A[z][M,K] @ B[z][N,K]^T  (bf16 in, f32 acc)
// 256x256 tile, BK=64, 8 waves (512 thr) as 2M x 4N (each wave 128x64 out),
// mfma_f32_16x16x32_bf16, double-buffered LDS (128 KiB), 2-phase pipeline:
//   STAGE(next tile) issued BEFORE compute(current); ONE __syncthreads per
//   K-tile (its vmcnt/lgkmcnt drain makes next buffer ready). [T3-min recipe]
// LDS layout K-slice-major [slice8][row256][8 bf16]: linear in global_load_lds
// slot order (dest = base + slot*16) AND conflict-free on ds_read_b128.
// EPI: 0 = bf16 store with scale (scores)
//      1 = bf16 store plain       (attn out)
//      2 = +bias, ReLU, bf16      (FFN1)
//      3 = +bias, f32 store       (FFN2)
// ---------------------------------------------------------------------------
template<int EPI>
__global__ __launch_bounds__(512, 2)
void gemm_nt(const bf16_t* __restrict__ A, const bf16_t* __restrict__ B,
             float* __restrict__ Cf, bf16_t* __restrict__ Cb,
             const float* __restrict__ bias, float scale,
             int M, int N, int K, long sA, long sB, long sC)
{
  __shared__ __align__(16) bf16_t Al[2][8][256][8];
  __shared__ __align__(16) bf16_t Bl[2][8][256][8];

  const int tid  = threadIdx.x;
  const int lane = tid & 63;
  const int wave = tid >> 6;          // 0..7
  const int bz   = blockIdx.z;

  const bf16_t* Ab = A + (long)bz * sA;
  const bf16_t* Bb = B + (long)bz * sB;

  const int bm = blockIdx.x * 256;
  const int bn = blockIdx.y * 256;
  const int wm = (wave >> 2) * 128;   // 2 M-halves
  const int wn = (wave & 3) * 64;     // 4 N-quarters

  f32x4 acc[8][4] = {};

  // staging: thread t, issue i -> LDS slot s = t + i*512 (16B each);
  // slot -> slice = s>>8, row = s&255; source = row's 8 bf16 at k-slice slc.
  const int srow = tid & 255;
  const int sslc = tid >> 8;          // 0 or 1; issue i adds 2i

  // fragment read coords: lane l holds rows (l&15), k = (l>>4)*8 + j
  const int fr = lane & 15;
  const int fs = lane >> 4;

  auto STAGE = [&](int bufi, int kt) {
#pragma unroll
    for (int i = 0; i < 4; i++) {
      const int slc = sslc + 2 * i;
      __builtin_amdgcn_global_load_lds(
        (const __attribute__((address_space(1))) void*)(Ab + (long)(bm + srow) * K + kt + slc * 8),
        (__attribute__((address_space(3))) void*)((char*)&Al[bufi][0][0][0] + (tid + i * 512) * 16),
        16, 0, 0);
    }
#pragma unroll
    for (int i = 0; i < 4; i++) {
      const int slc = sslc + 2 * i;
      __builtin_amdgcn_global_load_lds(
        (const __attribute__((address_space(1))) void*)(Bb + (long)(bn + srow) * K + kt + slc * 8),
        (__attribute__((address_space(3))) void*)((char*)&Bl[bufi][0][0][0] + (tid + i * 512) * 16),
        16, 0, 0);
    }
  };

  auto COMPUTE = [&](int bufi) {
#pragma unroll
    for (int kk = 0; kk < 2; kk++) {      // two 32-K steps per 64-K tile
      bf16x8 af[8], bfg[4];
#pragma unroll
      for (int m = 0; m < 8; m++)
        af[m] = *(const bf16x8*)&Al[bufi][4 * kk + fs][wm + m * 16 + fr][0];
#pragma unroll
      for (int n = 0; n < 4; n++)
        bfg[n] = *(const bf16x8*)&Bl[bufi][4 * kk + fs][wn + n * 16 + fr][0];
#pragma unroll
      for (int m = 0; m < 8; m++)
#pragma unroll
        for (int n = 0; n < 4; n++)
          acc[m][n] = __builtin_amdgcn_mfma_f32_16x16x32_bf16(af[m], bfg[n], acc[m][n], 0, 0, 0);
    }
  };

  // prologue
  STAGE(0, 0);
  __syncthreads();
  int buf = 0;
  for (int kt = 64; kt < K; kt += 64) {
    STAGE(buf ^ 1, kt);      // issue next-tile loads FIRST (latency hides
    COMPUTE(buf);            //   under this tile's ds_read + MFMA)
    __syncthreads();         // single drain per K-tile: next buffer ready
    buf ^= 1;
  }
  COMPUTE(buf);              // last tile, no prefetch

  // C/D layout (m89-verified): col = lane&15, row = (lane>>4)*4 + j
  const int r0 = bm + wm + ((lane >> 4) << 2);
  const int c0 = bn + wn + fr;
  const long cb = (long)bz * sC;
#pragma unroll
  for (int n = 0; n < 4; n++) {
    const int col = c0 + n * 16;
    float bv = 0.0f;
    if constexpr (EPI >= 2) bv = bias[col];
#pragma unroll
    for (int m = 0; m < 8; m++) {
#pragma unroll
      for (int j = 0; j < 4; j++) {
        const int row = r0 + m * 16 + j;
        const long idx = cb + (long)row * N + col;
        float v = acc[m][n][j];
        if constexpr (EPI == 0)      { Cb[idx] = f2bf(v * scale); }
        else if constexpr (EPI == 1) { Cb[idx] = f2bf(v); }
        else if constexpr (EPI == 2) { v += bv; Cb[idx] = f2bf(fmaxf(v, 0.0f)); }
        else                         { v += bv; Cf[idx] = v; }
      }
    }
  }
}

// ---------------------------------------------------------------------------
// Row softmax over S [(nb)*LQ][LKK] bf16 (already scaled) -> P bf16, in-place
// capable (P may == S). km/qm pointers pre-offset to the batch range.
// ---------------------------------------------------------------------------
__global__ __launch_bounds__(256)
void softmax_kernel(const bf16_t* __restrict__ S, bf16_t* __restrict__ P,
                    const float* __restrict__ km, const float* __restrict__ qm)
{
  __shared__ float red[8];
  const int r = blockIdx.x;
  const int b = r >> 11;              // local batch index (r / LQ)
  const int t = threadIdx.x;
  const bf16_t* row = S + (long)r * LKK;

  const bf16x8 sv = *(const bf16x8*)(row + t * 8);
  const float4 k0 = ((const float4*)(km + (long)b * LKK))[2 * t];
  const float4 k1 = ((const float4*)(km + (long)b * LKK))[2 * t + 1];
  const float kmv[8] = {k0.x, k0.y, k0.z, k0.w, k1.x, k1.y, k1.z, k1.w};

  float v[8];
  float mx = -3.4e38f;
#pragma unroll
  for (int i = 0; i < 8; i++) {
    float s = (float)sv[i];
    s = (kmv[i] == 0.0f) ? -4294967295.0f : s;   // NEG_INF
    v[i] = s;
    mx = fmaxf(mx, s);
  }
  mx = wred_max(mx);
  if ((t & 63) == 0) red[t >> 6] = mx;
  __syncthreads();
  mx = fmaxf(fmaxf(red[0], red[1]), fmaxf(red[2], red[3]));

  float sum = 0.0f;
#pragma unroll
  for (int i = 0; i < 8; i++) {
    const float e = __expf(v[i] - mx);
    v[i] = e;
    sum += e;
  }
  sum = wred_sum(sum);
  if ((t & 63) == 0) red[4 + (t >> 6)] = sum;
  __syncthreads();
  sum = red[4] + red[5] + red[6] + red[7];

  const float rs = qm[r] / sum;
  bf16x8 o;
#pragma unroll
  for (int i = 0; i < 8; i++) o[i] = f2bf(v[i] * rs);
  *(bf16x8*)(P + (long)r * LKK + t * 8) = o;
}

// ---------------------------------------------------------------------------
// Fused residual + LayerNorm: Y = LN(X + R)*w + b  (rows of EMBD)
// MODE bit0: X bf16 (else f32); bit1: R bf16; bit2: Y bf16 (else f32).
// In-place (Y==X) safe: per-thread same-address read-then-write.
// ---------------------------------------------------------------------------
template<int MODE>
__global__ __launch_bounds__(256)
void ln_kernel(const void* __restrict__ Xv, const void* __restrict__ Rv,
               const float* __restrict__ w, const float* __restrict__ bp,
               void* __restrict__ Yv)
{
  __shared__ float red[8];
  const long r = blockIdx.x;
  const int t = threadIdx.x;

  float x0, x1, x2, x3;
  if constexpr (MODE & 1) {
    const bf16x4 xv = ((const bf16x4*)((const bf16_t*)Xv + r * EMBD))[t];
    x0 = (float)xv[0]; x1 = (float)xv[1]; x2 = (float)xv[2]; x3 = (float)xv[3];
  } else {
    const float4 xv = ((const float4*)((const float*)Xv + r * EMBD))[t];
    x0 = xv.x; x1 = xv.y; x2 = xv.z; x3 = xv.w;
  }
  float r0, r1, r2, r3;
  if constexpr (MODE & 2) {
    const bf16x4 rv = ((const bf16x4*)((const bf16_t*)Rv + r * EMBD))[t];
    r0 = (float)rv[0]; r1 = (float)rv[1]; r2 = (float)rv[2]; r3 = (float)rv[3];
  } else {
    const float4 rv = ((const float4*)((const float*)Rv + r * EMBD))[t];
    r0 = rv.x; r1 = rv.y; r2 = rv.z; r3 = rv.w;
  }
  const float s0 = x0 + r0, s1 = x1 + r1, s2 = x2 + r2, s3 = x3 + r3;

  float sum = wred_sum(s0 + s1 + s2 + s3);
  if ((t & 63) == 0) red[t >> 6] = sum;
  __syncthreads();
  const float mu = (red[0] + red[1] + red[2] + red[3]) * (1.0f / EMBD);

  const float d0 = s0 - mu, d1 = s1 - mu, d2 = s2 - mu, d3 = s3 - mu;
  float sq = wred_sum(d0 * d0 + d1 * d1 + d2 * d2 + d3 * d3);
  if ((t & 63) == 0) red[4 + (t >> 6)] = sq;
  __syncthreads();
  const float var = (red[4] + red[5] + red[6] + red[7]) * (1.0f / EMBD);
  const float rstd = rsqrtf(var + 1e-5f);

  const float4 wv = ((const float4*)w)[t];
  const float4 bv = ((const float4*)bp)[t];
  const float y0 = d0 * rstd * wv.x + bv.x;
  const float y1 = d1 * rstd * wv.y + bv.y;
  const float y2 = d2 * rstd * wv.z + bv.z;
  const float y3 = d3 * rstd * wv.w + bv.w;

  if constexpr (MODE & 4) {
    bf16x4 o; o[0] = f2bf(y0); o[1] = f2bf(y1); o[2] = f2bf(y2); o[3] = f2bf(y3);
    ((bf16x4*)((bf16_t*)Yv + r * EMBD))[t] = o;
  } else {
    ((float4*)((float*)Yv + r * EMBD))[t] = make_float4(y0, y1, y2, y3);
  }
}

// flat f32 -> bf16 (vectorized, grid-stride)
__global__ void cvt_kernel(const float* __restrict__ in, bf16_t* __restrict__ out, long n4)
{
  long i = (long)blockIdx.x * 256 + threadIdx.x;
  const long stride = (long)gridDim.x * 256;
  for (; i < n4; i += stride) {
    const float4 v = ((const float4*)in)[i];
    bf16x4 o; o[0] = f2bf(v.x); o[1] = f2bf(v.y); o[2] = f2bf(v.z); o[3] = f2bf(v.w);
    ((bf16x4*)out)[i] = o;
  }
}

// batched [z][rows][cols] f32 -> [z][cols][rows] bf16 (tiled transpose via LDS)
__global__ __launch_bounds__(256)
void transpose_cvt(const float* __restrict__ in, bf16_t* __restrict__ out,
                   int rows, int cols)
{
  __shared__ bf16_t tile[32][33];
  const long zb = (long)blockIdx.z * rows * cols;
  const int cb = blockIdx.x * 32;      // col coord
  const int rb = blockIdx.y * 32;      // row coord
  const int tx = threadIdx.x & 31;
  const int ty = threadIdx.x >> 5;     // 0..7
#pragma unroll
  for (int i = 0; i < 4; i++) {
    const int rr = ty + i * 8;
    tile[rr][tx] = f2bf(in[zb + (long)(rb + rr) * cols + cb + tx]);
  }
  __syncthreads();
#pragma unroll
  for (int i = 0; i < 4; i++) {
    const int cc = ty + i * 8;
    out[zb + (long)(cb + cc) * rows + rb + tx] = tile[tx][cc];
  }
}

// ---------------------------------------------------------------------------
extern "C" void kernel_launch(void* const* d_in, const int* in_sizes, int n_in,
                              void* d_out, int out_size, void* d_ws, size_t ws_size,
                              hipStream_t stream)
{
  const float* q    = (const float*)d_in[0];
  const float* k    = (const float*)d_in[1];
  const float* qm   = (const float*)d_in[2];
  const float* km   = (const float*)d_in[3];
  const float* lnw  = (const float*)d_in[4];
  const float* lnb  = (const float*)d_in[5];
  const float* ln2w = (const float*)d_in[6];
  const float* ln2b = (const float*)d_in[7];
  const float* W1   = (const float*)d_in[8];
  const float* b1   = (const float*)d_in[9];
  const float* W2   = (const float*)d_in[10];
  const float* b2   = (const float*)d_in[11];

  char* ws = (char*)d_ws;
  char* ob = (char*)d_out;
  const float scale = 0.03125f;             // 1/(sqrt(1024)+1e-8)
  const long MB = 1L << 20;
  const long QE = (long)LQ * EMBD;          // 2M elems per batch (Q-shaped)
  const long SS = (long)LQ * LKK;           // 4M elems per batch (S-shaped)

  if (ws_size >= 100 * MB) {
    // ================= Tier A: fully batched (z=8) =================
    // ws:  [0,32) Qb -> attn   [32,64) Kb -> h   [64,96) Kt   [96,100) W1b,W2b
    // out: [0,64) S/P bf16 (in-place softmax) -> y f32
    bf16_t* Qb   = (bf16_t*)ws;
    bf16_t* attn = (bf16_t*)ws;                  // overlays Qb (dead after QK)
    bf16_t* Kb   = (bf16_t*)(ws + 32 * MB);
    bf16_t* h    = (bf16_t*)(ws + 32 * MB);      // overlays Kb (dead after QK)
    bf16_t* Kt   = (bf16_t*)(ws + 64 * MB);
    bf16_t* W1b  = (bf16_t*)(ws + 96 * MB);
    bf16_t* W2b  = (bf16_t*)(ws + 98 * MB);
    bf16_t* Sb   = (bf16_t*)ob;                  // 64 MiB, whole d_out
    float*  y    = (float*)ob;

    cvt_kernel<<<1024, 256, 0, stream>>>(W1, W1b, (long)EMBD * EMBD / 4);
    cvt_kernel<<<1024, 256, 0, stream>>>(W2, W2b, (long)EMBD * EMBD / 4);
    cvt_kernel<<<4096, 256, 0, stream>>>(q, Qb, (long)NB * QE / 4);
    cvt_kernel<<<4096, 256, 0, stream>>>(k, Kb, (long)NB * QE / 4);
    transpose_cvt<<<dim3(EMBD / 32, LKK / 32, NB), 256, 0, stream>>>(k, Kt, LKK, EMBD);

    // S = (Q K^T)/32
    gemm_nt<0><<<dim3(LQ / 256, LKK / 256, NB), 512, 0, stream>>>(
        Qb, Kb, nullptr, Sb, nullptr, scale, LQ, LKK, EMBD, QE, QE, SS);
    // P = qmask * softmax(mask(S))   (in-place)
    softmax_kernel<<<NB * LQ, 256, 0, stream>>>(Sb, Sb, km, qm);
    // attn = P @ K
    gemm_nt<1><<<dim3(LQ / 256, EMBD / 256, NB), 512, 0, stream>>>(
        Sb, Kt, nullptr, attn, nullptr, 0.0f, LQ, EMBD, LKK, SS, (long)EMBD * LKK, QE);
    // x = LN(attn + q) in-place
    ln_kernel<5><<<NB * LQ, 256, 0, stream>>>(attn, q, lnw, lnb, attn);
    // FFN single-shot over 16384 rows
    gemm_nt<2><<<dim3(NB * LQ / 256, EMBD / 256, 1), 512, 0, stream>>>(
        attn, W1b, nullptr, h, b1, 0.0f, NB * LQ, EMBD, EMBD, 0, 0, 0);
    gemm_nt<3><<<dim3(NB * LQ / 256, EMBD / 256, 1), 512, 0, stream>>>(
        h, W2b, y, nullptr, b2, 0.0f, NB * LQ, EMBD, EMBD, 0, 0, 0);
    // out = LN(y + x) in-place
    ln_kernel<2><<<NB * LQ, 256, 0, stream>>>(y, attn, ln2w, ln2b, y);

  } else if (ws_size >= 52 * MB) {
    // ================= Tier B: two half-batches (z=4) =================
    bf16_t* attn = (bf16_t*)ws;
    bf16_t* W1b  = (bf16_t*)(ws + 32 * MB);
    bf16_t* W2b  = (bf16_t*)(ws + 34 * MB);
    bf16_t* Kth  = (bf16_t*)(ws + 36 * MB);
    bf16_t* h    = (bf16_t*)(ws + 36 * MB);      // overlays Kth (dead after PV)
    bf16_t* Sb   = (bf16_t*)ob;
    bf16_t* Qbh  = (bf16_t*)(ob + 32 * MB);
    bf16_t* Kbh  = (bf16_t*)(ob + 48 * MB);
    float*  y    = (float*)ob;

    cvt_kernel<<<1024, 256, 0, stream>>>(W1, W1b, (long)EMBD * EMBD / 4);
    cvt_kernel<<<1024, 256, 0, stream>>>(W2, W2b, (long)EMBD * EMBD / 4);

    for (int it = 0; it < 2; it++) {
      const int bo = it * 4;
      const float* qh = q + bo * QE;
      const float* kh = k + bo * QE;
      cvt_kernel<<<2048, 256, 0, stream>>>(qh, Qbh, 4 * QE / 4);
      cvt_kernel<<<2048, 256, 0, stream>>>(kh, Kbh, 4 * QE / 4);
      transpose_cvt<<<dim3(EMBD / 32, LKK / 32, 4), 256, 0, stream>>>(kh, Kth, LKK, EMBD);

      gemm_nt<0><<<dim3(LQ / 256, LKK / 256, 4), 512, 0, stream>>>(
          Qbh, Kbh, nullptr, Sb, nullptr, scale, LQ, LKK, EMBD, QE, QE, SS);
      softmax_kernel<<<4 * LQ, 256, 0, stream>>>(Sb, Sb, km + bo * LKK, qm + bo * LQ);
      gemm_nt<1><<<dim3(LQ / 256, EMBD / 256, 4), 512, 0, stream>>>(
          Sb, Kth, nullptr, attn + bo * QE, nullptr, 0.0f, LQ, EMBD, LKK,
          SS, (long)EMBD * LKK, QE);
    }
    ln_kernel<5><<<NB * LQ, 256, 0, stream>>>(attn, q, lnw, lnb, attn);
    for (int c = 0; c < 2; c++) {
      bf16_t* xc = attn + (long)c * 8192 * EMBD;
      float*  yc = y + (long)c * 8192 * EMBD;
      gemm_nt<2><<<dim3(8192 / 256, EMBD / 256, 1), 512, 0, stream>>>(
          xc, W1b, nullptr, h, b1, 0.0f, 8192, EMBD, EMBD, 0, 0, 0);
      gemm_nt<3><<<dim3(8192 / 256, EMBD / 256, 1), 512, 0, stream>>>(
          h, W2b, yc, nullptr, b2, 0.0f, 8192, EMBD, EMBD, 0, 0, 0);
    }
    ln_kernel<2><<<NB * LQ, 256, 0, stream>>>(y, attn, ln2w, ln2b, y);

  } else {
    // ================= Tier C: per-batch 44 MiB fallback =================
    if (ws_size < 44 * MB) return;
    bf16_t* attn = (bf16_t*)ws;
    bf16_t* W1b  = (bf16_t*)(ws + 32 * MB);
    bf16_t* W2b  = (bf16_t*)(ws + 34 * MB);
    bf16_t* h    = (bf16_t*)(ws + 36 * MB);
    bf16_t* Sb   = (bf16_t*)(ob);
    bf16_t* Pb   = (bf16_t*)(ob + 8 * MB);
    bf16_t* Qbb  = (bf16_t*)(ob + 16 * MB);
    bf16_t* Kbb  = (bf16_t*)(ob + 20 * MB);
    bf16_t* Ktb  = (bf16_t*)(ob + 24 * MB);

    cvt_kernel<<<1024, 256, 0, stream>>>(W1, W1b, (long)EMBD * EMBD / 4);
    cvt_kernel<<<1024, 256, 0, stream>>>(W2, W2b, (long)EMBD * EMBD / 4);

    for (int b = 0; b < NB; b++) {
      const float* qb = q + b * QE;
      const float* kb = k + b * QE;
      cvt_kernel<<<2048, 256, 0, stream>>>(qb, Qbb, QE / 4);
      cvt_kernel<<<2048, 256, 0, stream>>>(kb, Kbb, QE / 4);
      transpose_cvt<<<dim3(EMBD / 32, LKK / 32, 1), 256, 0, stream>>>(kb, Ktb, LKK, EMBD);

      gemm_nt<0><<<dim3(LQ / 256, LKK / 256, 1), 512, 0, stream>>>(
          Qbb, Kbb, nullptr, Sb, nullptr, scale, LQ, LKK, EMBD, 0, 0, 0);
      softmax_kernel<<<LQ, 256, 0, stream>>>(Sb, Pb, km + (long)b * LKK, qm + (long)b * LQ);
      gemm_nt<1><<<dim3(LQ / 256, EMBD / 256, 1), 512, 0, stream>>>(
          Pb, Ktb, nullptr, attn + b * QE, nullptr, 0.0f, LQ, EMBD, LKK, 0, 0, 0);
    }
    ln_kernel<5><<<NB * LQ, 256, 0, stream>>>(attn, q, lnw, lnb, attn);
    for (int c = 0; c < 4; c++) {
      bf16_t* xc = attn + (long)c * 4096 * EMBD;
      float*  yc = (float*)d_out + (long)c * 4096 * EMBD;
      gemm_nt<2><<<dim3(4096 / 256, EMBD / 256, 1), 512, 0, stream>>>(
          xc, W1b, nullptr, h, b1, 0.0f, 4096, EMBD, EMBD, 0, 0, 0);
      gemm_nt<3><<<dim3(4096 / 256, EMBD / 256, 1), 512, 0, stream>>>(
          h, W2b, yc, nullptr, b2, 0.0f, 4096, EMBD, EMBD, 0, 0, 0);
      ln_kernel<2><<<4096, 256, 0, stream>>>(yc, xc, ln2w, ln2b, yc);
    }
  }
}